// Round 2
// baseline (402.419 us; speedup 1.0000x reference)
//
#include <hip/hip_runtime.h>
#include <hip/hip_bf16.h>
#include <stdint.h>

#define BB 16
#define TT 1024
#define DD 256

typedef __attribute__((ext_vector_type(8))) short short8;
typedef __attribute__((ext_vector_type(4))) float floatx4;

__device__ __forceinline__ unsigned short f2bf(float f) {
    union { float f; unsigned int u; } c; c.f = f;
    unsigned int u = c.u;
    unsigned int r = (u + 0x7FFFu + ((u >> 16) & 1u)) >> 16;
    return (unsigned short)r;
}

// One 64-lane wave per row of z (D=256 -> 4 floats/lane).
// Also zeroes the global double accumulator.
__global__ __launch_bounds__(256) void prep_kernel(
    const float* __restrict__ z, float* __restrict__ z2,
    unsigned short* __restrict__ zb, double* __restrict__ acc) {
    if (blockIdx.x == 0 && threadIdx.x == 0) *acc = 0.0;
    const int lane = threadIdx.x & 63;
    const int row  = blockIdx.x * 4 + (threadIdx.x >> 6);   // [0, BB*TT)
    const float4 v = ((const float4*)(z + (size_t)row * DD))[lane];
    float ss = v.x * v.x + v.y * v.y + v.z * v.z + v.w * v.w;
    ushort4 o;
    o.x = f2bf(v.x); o.y = f2bf(v.y); o.z = f2bf(v.z); o.w = f2bf(v.w);
    ((ushort4*)(zb + (size_t)row * DD))[lane] = o;
#pragma unroll
    for (int off = 32; off > 0; off >>= 1) ss += __shfl_down(ss, off);
    if (lane == 0) z2[row] = ss;
}

// One wave = one 32x32 (t,s) tile. gt loads hoisted ABOVE the MFMA loop so
// the HBM stream (the roofline resource) is in flight while MFMA runs.
// A-frag: lane holds z[t0 + (lane&15)][kstep*32 + (lane>>4)*8 .. +7]
// C/D:    G[t0 + (lane>>4)*4 + r][s0 + (lane&15)]   [m89/m91 layout]
__global__ __launch_bounds__(256) void patch_kernel(
    const unsigned short* __restrict__ zb, const float* __restrict__ z2,
    const float* __restrict__ gt, const float* __restrict__ sigma,
    double* __restrict__ acc) {
    const float LOG2E = 1.4426950408889634f;
    const float s0v = sigma[0], s1v = sigma[1], s2v = sigma[2], s3v = sigma[3];
    // negative coefficients: kern' = -log2e/(2s^2) * d^2, w = exp2(kern')
    const float nc0 = -LOG2E * 0.5f / (s0v * s0v);
    const float nc1 = -LOG2E * 0.5f / (s1v * s1v);
    const float nc2 = -LOG2E * 0.5f / (s2v * s2v);
    const float nc3 = -LOG2E * 0.5f / (s3v * s3v);

    const int tid  = threadIdx.x;
    const int lane = tid & 63;
    const int quad = lane >> 4;
    const int m    = lane & 15;
    const int wid  = blockIdx.x * 4 + (tid >> 6);   // [0, 16384) == one tile

    const int b   = wid >> 10;
    const int rem = wid & 1023;
    const int t0  = (rem >> 5) << 5;
    const int s0  = (rem & 31) << 5;

    const float* gtb = gt + (size_t)b * TT * TT * 4;
    const int    tq  = t0 + quad * 4;

    // ---- issue ALL 16 gt float4 loads first (independent of MFMA) ----
    float4 gtv[16];
#pragma unroll
    for (int r = 0; r < 4; ++r) {
        const size_t row0 = (size_t)(tq + r) * TT;
        const size_t row1 = (size_t)(tq + 16 + r) * TT;
        gtv[r * 4 + 0] = *(const float4*)(gtb + (row0 + (s0 + m)) * 4);
        gtv[r * 4 + 1] = *(const float4*)(gtb + (row0 + (s0 + 16 + m)) * 4);
        gtv[r * 4 + 2] = *(const float4*)(gtb + (row1 + (s0 + m)) * 4);
        gtv[r * 4 + 3] = *(const float4*)(gtb + (row1 + (s0 + 16 + m)) * 4);
    }

    // ---- Gram tile via MFMA while gt stream is in flight ----
    const unsigned short* zrow = zb + (size_t)b * TT * DD;
    const short8* at0 = (const short8*)(zrow + (t0 + m) * DD + quad * 8);
    const short8* at1 = (const short8*)(zrow + (t0 + 16 + m) * DD + quad * 8);
    const short8* bs0 = (const short8*)(zrow + (s0 + m) * DD + quad * 8);
    const short8* bs1 = (const short8*)(zrow + (s0 + 16 + m) * DD + quad * 8);

    floatx4 g00 = {0.f, 0.f, 0.f, 0.f};
    floatx4 g01 = {0.f, 0.f, 0.f, 0.f};
    floatx4 g10 = {0.f, 0.f, 0.f, 0.f};
    floatx4 g11 = {0.f, 0.f, 0.f, 0.f};
#pragma unroll
    for (int k = 0; k < 8; ++k) {
        const short8 a0 = at0[k * 4];
        const short8 a1 = at1[k * 4];
        const short8 b0 = bs0[k * 4];
        const short8 b1 = bs1[k * 4];
        g00 = __builtin_amdgcn_mfma_f32_16x16x32_bf16(a0, b0, g00, 0, 0, 0);
        g01 = __builtin_amdgcn_mfma_f32_16x16x32_bf16(a0, b1, g01, 0, 0, 0);
        g10 = __builtin_amdgcn_mfma_f32_16x16x32_bf16(a1, b0, g10, 0, 0, 0);
        g11 = __builtin_amdgcn_mfma_f32_16x16x32_bf16(a1, b1, g11, 0, 0, 0);
    }

    // ---- epilogue: w = exp2(sum nc_k d_k^2); partial += w*(z2t+z2s-2G) ----
    const float* z2b  = z2 + b * TT;
    const float  z2s0 = z2b[s0 + m];
    const float  z2s1 = z2b[s0 + 16 + m];

    float partial = 0.f;
#pragma unroll
    for (int r = 0; r < 4; ++r) {
        const float z2t0 = z2b[tq + r];
        const float z2t1 = z2b[tq + 16 + r];
        const float e00 = z2t0 + z2s0, e01 = z2t0 + z2s1;
        const float e10 = z2t1 + z2s0, e11 = z2t1 + z2s1;
        {
            const float4 d = gtv[r * 4 + 0];
            const float k2 = fmaf(nc3, d.w * d.w, fmaf(nc2, d.z * d.z,
                             fmaf(nc1, d.y * d.y, nc0 * d.x * d.x)));
            partial = fmaf(exp2f(k2), fmaf(-2.f, g00[r], e00), partial);
        }
        {
            const float4 d = gtv[r * 4 + 1];
            const float k2 = fmaf(nc3, d.w * d.w, fmaf(nc2, d.z * d.z,
                             fmaf(nc1, d.y * d.y, nc0 * d.x * d.x)));
            partial = fmaf(exp2f(k2), fmaf(-2.f, g01[r], e01), partial);
        }
        {
            const float4 d = gtv[r * 4 + 2];
            const float k2 = fmaf(nc3, d.w * d.w, fmaf(nc2, d.z * d.z,
                             fmaf(nc1, d.y * d.y, nc0 * d.x * d.x)));
            partial = fmaf(exp2f(k2), fmaf(-2.f, g10[r], e10), partial);
        }
        {
            const float4 d = gtv[r * 4 + 3];
            const float k2 = fmaf(nc3, d.w * d.w, fmaf(nc2, d.z * d.z,
                             fmaf(nc1, d.y * d.y, nc0 * d.x * d.x)));
            partial = fmaf(exp2f(k2), fmaf(-2.f, g11[r], e11), partial);
        }
    }

    // wave reduce (64 lanes) then block reduce -> one double atomic per block
#pragma unroll
    for (int off = 32; off > 0; off >>= 1) partial += __shfl_down(partial, off);
    __shared__ float red[4];
    if (lane == 0) red[tid >> 6] = partial;
    __syncthreads();
    if (tid == 0) atomicAdd(acc, (double)(red[0] + red[1] + red[2] + red[3]));
}

__global__ void finalize_kernel(const double* __restrict__ acc, float* __restrict__ out) {
    out[0] = (float)(*acc * (1.0 / ((double)BB * (double)TT * (double)TT)));
}

extern "C" void kernel_launch(void* const* d_in, const int* in_sizes, int n_in,
                              void* d_out, int out_size, void* d_ws, size_t ws_size,
                              hipStream_t stream) {
    const float* z     = (const float*)d_in[0];   // [16,1024,256]
    const float* gt    = (const float*)d_in[1];   // [16,1024,1024,4]
    const float* sigma = (const float*)d_in[2];   // [4]
    float* out = (float*)d_out;

    char* ws = (char*)d_ws;
    double* acc        = (double*)ws;
    float* z2          = (float*)(ws + 64);
    unsigned short* zb = (unsigned short*)(ws + 64 + (size_t)BB * TT * sizeof(float));

    prep_kernel<<<BB * TT / 4, 256, 0, stream>>>(z, z2, zb, acc);
    patch_kernel<<<BB * (TT / 32) * (TT / 32) / 4, 256, 0, stream>>>(zb, z2, gt, sigma, acc);
    finalize_kernel<<<1, 1, 0, stream>>>(acc, out);
}

// Round 3
// 386.209 us; speedup vs baseline: 1.0420x; 1.0420x over previous
//
#include <hip/hip_runtime.h>
#include <hip/hip_bf16.h>
#include <stdint.h>

#define BB 16
#define TT 1024
#define DD 256
#define NACC 64   // spread accumulator slots (reduces same-address atomic serialization)

typedef __attribute__((ext_vector_type(8))) short short8;
typedef __attribute__((ext_vector_type(4))) float floatx4;
typedef __attribute__((ext_vector_type(4))) float fvec4;   // builtin-compatible float4

__device__ __forceinline__ unsigned short f2bf(float f) {
    union { float f; unsigned int u; } c; c.f = f;
    unsigned int u = c.u;
    unsigned int r = (u + 0x7FFFu + ((u >> 16) & 1u)) >> 16;
    return (unsigned short)r;
}

// One 64-lane wave per row of z (D=256 -> 4 floats/lane).
// Also zeroes the 64 global double accumulator slots.
__global__ __launch_bounds__(256) void prep_kernel(
    const float* __restrict__ z, float* __restrict__ z2,
    unsigned short* __restrict__ zb, double* __restrict__ acc) {
    if (blockIdx.x == 0 && threadIdx.x < NACC) acc[threadIdx.x] = 0.0;
    const int lane = threadIdx.x & 63;
    const int row  = blockIdx.x * 4 + (threadIdx.x >> 6);   // [0, BB*TT)
    const float4 v = ((const float4*)(z + (size_t)row * DD))[lane];
    float ss = v.x * v.x + v.y * v.y + v.z * v.z + v.w * v.w;
    ushort4 o;
    o.x = f2bf(v.x); o.y = f2bf(v.y); o.z = f2bf(v.z); o.w = f2bf(v.w);
    ((ushort4*)(zb + (size_t)row * DD))[lane] = o;
#pragma unroll
    for (int off = 32; off > 0; off >>= 1) ss += __shfl_down(ss, off);
    if (lane == 0) z2[row] = ss;
}

// One wave = one 32x32 (t,s) tile.
//  - gt streamed with NONTEMPORAL loads (read-once; keep L2 for zb reuse)
//  - epilogue split in two 8-float4 halves: peak gt liveness 32 VGPRs, not 64
//  - Gram tile via 2x2 mfma_f32_16x16x32_bf16 over D=256
// A-frag: lane holds z[t0 + (lane&15)][kstep*32 + (lane>>4)*8 .. +7]
// C/D:    G[t0 + (lane>>4)*4 + r][s0 + (lane&15)]   [m89/m91 layout]
__global__ __launch_bounds__(256) void patch_kernel(
    const unsigned short* __restrict__ zb, const float* __restrict__ z2,
    const float* __restrict__ gt, const float* __restrict__ sigma,
    double* __restrict__ acc) {
    const float LOG2E = 1.4426950408889634f;
    const float s0v = sigma[0], s1v = sigma[1], s2v = sigma[2], s3v = sigma[3];
    const float nc0 = -LOG2E * 0.5f / (s0v * s0v);
    const float nc1 = -LOG2E * 0.5f / (s1v * s1v);
    const float nc2 = -LOG2E * 0.5f / (s2v * s2v);
    const float nc3 = -LOG2E * 0.5f / (s3v * s3v);

    const int tid  = threadIdx.x;
    const int lane = tid & 63;
    const int quad = lane >> 4;
    const int m    = lane & 15;
    const int wid  = blockIdx.x * 4 + (tid >> 6);   // one 32x32 tile per wave

    const int b   = wid >> 10;
    const int rem = wid & 1023;
    const int t0  = (rem >> 5) << 5;
    const int s0  = (rem & 31) << 5;

    const float* gtb = gt + (size_t)b * TT * TT * 4;
    const int    tq  = t0 + quad * 4;

    // ---- half 1 of gt stream: rows r=0,1 (8 x float4, nontemporal) ----
    fvec4 gtv[8];
#pragma unroll
    for (int r = 0; r < 2; ++r) {
        const size_t row0 = (size_t)(tq + r) * TT;
        const size_t row1 = (size_t)(tq + 16 + r) * TT;
        gtv[r * 4 + 0] = __builtin_nontemporal_load((const fvec4*)(gtb + (row0 + (s0 + m)) * 4));
        gtv[r * 4 + 1] = __builtin_nontemporal_load((const fvec4*)(gtb + (row0 + (s0 + 16 + m)) * 4));
        gtv[r * 4 + 2] = __builtin_nontemporal_load((const fvec4*)(gtb + (row1 + (s0 + m)) * 4));
        gtv[r * 4 + 3] = __builtin_nontemporal_load((const fvec4*)(gtb + (row1 + (s0 + 16 + m)) * 4));
    }

    // ---- Gram tile via MFMA (overlaps with gt stream) ----
    const unsigned short* zrow = zb + (size_t)b * TT * DD;
    const short8* at0 = (const short8*)(zrow + (t0 + m) * DD + quad * 8);
    const short8* at1 = (const short8*)(zrow + (t0 + 16 + m) * DD + quad * 8);
    const short8* bs0 = (const short8*)(zrow + (s0 + m) * DD + quad * 8);
    const short8* bs1 = (const short8*)(zrow + (s0 + 16 + m) * DD + quad * 8);

    floatx4 g00 = {0.f, 0.f, 0.f, 0.f};
    floatx4 g01 = {0.f, 0.f, 0.f, 0.f};
    floatx4 g10 = {0.f, 0.f, 0.f, 0.f};
    floatx4 g11 = {0.f, 0.f, 0.f, 0.f};
#pragma unroll
    for (int k = 0; k < 8; ++k) {
        const short8 a0 = at0[k * 4];
        const short8 a1 = at1[k * 4];
        const short8 b0 = bs0[k * 4];
        const short8 b1 = bs1[k * 4];
        g00 = __builtin_amdgcn_mfma_f32_16x16x32_bf16(a0, b0, g00, 0, 0, 0);
        g01 = __builtin_amdgcn_mfma_f32_16x16x32_bf16(a0, b1, g01, 0, 0, 0);
        g10 = __builtin_amdgcn_mfma_f32_16x16x32_bf16(a1, b0, g10, 0, 0, 0);
        g11 = __builtin_amdgcn_mfma_f32_16x16x32_bf16(a1, b1, g11, 0, 0, 0);
    }

    const float* z2b  = z2 + b * TT;
    const float  z2s0 = z2b[s0 + m];
    const float  z2s1 = z2b[s0 + 16 + m];

    float partial = 0.f;

    // ---- epilogue half 1 (r=0,1), then stream+consume half 2 (r=2,3) ----
#pragma unroll
    for (int half = 0; half < 2; ++half) {
        if (half == 1) {
#pragma unroll
            for (int r = 0; r < 2; ++r) {
                const size_t row0 = (size_t)(tq + 2 + r) * TT;
                const size_t row1 = (size_t)(tq + 18 + r) * TT;
                gtv[r * 4 + 0] = __builtin_nontemporal_load((const fvec4*)(gtb + (row0 + (s0 + m)) * 4));
                gtv[r * 4 + 1] = __builtin_nontemporal_load((const fvec4*)(gtb + (row0 + (s0 + 16 + m)) * 4));
                gtv[r * 4 + 2] = __builtin_nontemporal_load((const fvec4*)(gtb + (row1 + (s0 + m)) * 4));
                gtv[r * 4 + 3] = __builtin_nontemporal_load((const fvec4*)(gtb + (row1 + (s0 + 16 + m)) * 4));
            }
        }
#pragma unroll
        for (int r = 0; r < 2; ++r) {
            const int rr = half * 2 + r;
            const float z2t0 = z2b[tq + rr];
            const float z2t1 = z2b[tq + 16 + rr];
            const float e00 = z2t0 + z2s0, e01 = z2t0 + z2s1;
            const float e10 = z2t1 + z2s0, e11 = z2t1 + z2s1;
            {
                const fvec4 d = gtv[r * 4 + 0];
                const float k2 = fmaf(nc3, d.w * d.w, fmaf(nc2, d.z * d.z,
                                 fmaf(nc1, d.y * d.y, nc0 * d.x * d.x)));
                partial = fmaf(exp2f(k2), fmaf(-2.f, g00[rr], e00), partial);
            }
            {
                const fvec4 d = gtv[r * 4 + 1];
                const float k2 = fmaf(nc3, d.w * d.w, fmaf(nc2, d.z * d.z,
                                 fmaf(nc1, d.y * d.y, nc0 * d.x * d.x)));
                partial = fmaf(exp2f(k2), fmaf(-2.f, g01[rr], e01), partial);
            }
            {
                const fvec4 d = gtv[r * 4 + 2];
                const float k2 = fmaf(nc3, d.w * d.w, fmaf(nc2, d.z * d.z,
                                 fmaf(nc1, d.y * d.y, nc0 * d.x * d.x)));
                partial = fmaf(exp2f(k2), fmaf(-2.f, g10[rr], e10), partial);
            }
            {
                const fvec4 d = gtv[r * 4 + 3];
                const float k2 = fmaf(nc3, d.w * d.w, fmaf(nc2, d.z * d.z,
                                 fmaf(nc1, d.y * d.y, nc0 * d.x * d.x)));
                partial = fmaf(exp2f(k2), fmaf(-2.f, g11[rr], e11), partial);
            }
        }
    }

    // wave reduce, block reduce, one double atomic per block into a spread slot
#pragma unroll
    for (int off = 32; off > 0; off >>= 1) partial += __shfl_down(partial, off);
    __shared__ float red[4];
    if (lane == 0) red[tid >> 6] = partial;
    __syncthreads();
    if (tid == 0)
        atomicAdd(&acc[blockIdx.x & (NACC - 1)],
                  (double)(red[0] + red[1] + red[2] + red[3]));
}

__global__ void finalize_kernel(const double* __restrict__ acc, float* __restrict__ out) {
    double v = acc[threadIdx.x];   // 64 threads = 1 wave
#pragma unroll
    for (int off = 32; off > 0; off >>= 1) v += __shfl_down(v, off);
    if (threadIdx.x == 0)
        out[0] = (float)(v * (1.0 / ((double)BB * (double)TT * (double)TT)));
}

extern "C" void kernel_launch(void* const* d_in, const int* in_sizes, int n_in,
                              void* d_out, int out_size, void* d_ws, size_t ws_size,
                              hipStream_t stream) {
    const float* z     = (const float*)d_in[0];   // [16,1024,256]
    const float* gt    = (const float*)d_in[1];   // [16,1024,1024,4]
    const float* sigma = (const float*)d_in[2];   // [4]
    float* out = (float*)d_out;

    // ws: [0,512)=64 double acc slots | 512: z2 (64 KB) | 66048: zb (8 MB bf16)
    char* ws = (char*)d_ws;
    double* acc        = (double*)ws;
    float* z2          = (float*)(ws + 512);
    unsigned short* zb = (unsigned short*)(ws + 512 + (size_t)BB * TT * sizeof(float));

    prep_kernel<<<BB * TT / 4, 256, 0, stream>>>(z, z2, zb, acc);
    patch_kernel<<<BB * (TT / 32) * (TT / 32) / 4, 256, 0, stream>>>(zb, z2, gt, sigma, acc);
    finalize_kernel<<<1, 64, 0, stream>>>(acc, out);
}